// Round 7
// baseline (183.332 us; speedup 1.0000x reference)
//
#include <hip/hip_runtime.h>
#include <hip/hip_bf16.h>
#include <stdint.h>

#define T_TOKENS 8192
#define D_DIM 1024
#define H_DIM 2048
#define N_EXPERTS 8

typedef __attribute__((ext_vector_type(8))) short bf16x8;
typedef __attribute__((ext_vector_type(4))) float f32x4;

typedef __attribute__((address_space(1))) const void* gptr_t;
typedef __attribute__((address_space(3))) void* lptr_t;

__device__ __forceinline__ unsigned short f2bf(float f) {
  union { float f; unsigned int u; } x; x.f = f;
  unsigned int r = x.u + 0x7FFFu + ((x.u >> 16) & 1u);
  return (unsigned short)(r >> 16);
}
__device__ __forceinline__ float bf2f(unsigned short b) {
  union { unsigned int u; float f; } x; x.u = ((unsigned int)b) << 16;
  return x.f;
}

__device__ __forceinline__ void gload16(const void* g, void* l) {
  __builtin_amdgcn_global_load_lds((gptr_t)g, (lptr_t)l, 16, 0, 0);
}

// Sync discipline (rule #18: sched_barrier after inline-asm waits / raw barriers)
#define SBAR()   do { __builtin_amdgcn_s_barrier(); __builtin_amdgcn_sched_barrier(0); } while (0)
#define LGKM0()  do { asm volatile("s_waitcnt lgkmcnt(0)" ::: "memory"); __builtin_amdgcn_sched_barrier(0); } while (0)
#define LGKMN(n) do { asm volatile("s_waitcnt lgkmcnt(" #n ")" ::: "memory"); __builtin_amdgcn_sched_barrier(0); } while (0)
#define VMW(n)   do { __builtin_amdgcn_sched_barrier(0); asm volatile("s_waitcnt vmcnt(" #n ")" ::: "memory"); } while (0)

// ---------------------------------------------------------------------------
// fp32 -> bf16 conversion — round-1 structure (measured ~36us for all three;
// that is the 240MB @ 6.3TB/s roofline for this pass).
// ---------------------------------------------------------------------------
__global__ void cvt_f32_bf16_kernel(const float* __restrict__ in,
                                    unsigned short* __restrict__ out, int n) {
  int tid = blockIdx.x * blockDim.x + threadIdx.x;
  int stride = gridDim.x * blockDim.x;
  for (int i = tid * 4; i < n; i += stride * 4) {
    const float4 v = *reinterpret_cast<const float4*>(in + i);
    ushort4 o;
    o.x = f2bf(v.x); o.y = f2bf(v.y); o.z = f2bf(v.z); o.w = f2bf(v.w);
    *reinterpret_cast<ushort4*>(out + i) = o;
  }
}

// ---------------------------------------------------------------------------
// GEMM1 (new geometry): hsq[T,H] = bf16(relu(bf16(x @ w_up^T))^2).
// BM=256 BN=256 BK=64, 8 waves 2Mx4N, WAVE-TILE 128x64 (acc[8][4]).
// LDS-read/MFMA ratio 0.375 KB/MFMA (vs 0.5 at 64x64) -> MFMA-dominant.
// LDS ring-2 full K-tiles: lA 2x[256][64] (64KB) + lB 2x[256][64] (64KB).
// Per tile: VMW(8) (1-tile prefetch in flight, never drains to 0 mid-loop),
// SBAR, 24 ds_read_b128, 64 MFMA (2 kk clusters), SBAR, stage(t+2).
// Arrival: per-wave vmcnt(8) forces own t-lines done, barrier makes it global.
// WAR: stage(t+2) into buf[t&1] only after SBAR2 = all waves' reads retired.
// XOR swizzle (rule #21): rows are 128B (8 granules); stage pre-swizzles the
// GLOBAL granule (lane&7)^(lane>>3), LDS dest linear; read granule
// (kk*4+rg) ^ (row&7) -> 2-way on ds_read_b128 = free (m136).
// ---------------------------------------------------------------------------
__global__ __launch_bounds__(512, 2)
void gg1_256(const unsigned short* __restrict__ A,  // (T, D) bf16
             const unsigned short* __restrict__ B,  // (E, H, D) bf16
             const int* __restrict__ counts,
             unsigned short* __restrict__ O) {      // (T, H) bf16
  constexpr int K = D_DIM;
  constexpr int NT = K / 64;      // 16
  constexpr int AT = 256 * 64;    // shorts per tile buffer
  __shared__ short lA[2 * AT];    // 64 KB
  __shared__ short lB[2 * AT];    // 64 KB

  const int tid = threadIdx.x;
  const int wid = tid >> 6, lane = tid & 63;
  const int wr = wid >> 2, wc = wid & 3;          // 2M x 4N
  const int bid = blockIdx.x;
  const int cb = bid & 7, rb = bid >> 3;          // cb <-> XCD (grid 256)
  const int r0 = rb * 256, c0 = cb * 256;

  int csum[N_EXPERTS + 1];
  csum[0] = 0;
  for (int e = 0; e < N_EXPERTS; ++e) csum[e + 1] = csum[e] + counts[e];
  int eLo = 0;
  while (eLo < N_EXPERTS - 1 && csum[eLo + 1] <= r0) ++eLo;
  int eHi = eLo;
  while (eHi < N_EXPERTS - 1 && csum[eHi + 1] < r0 + 256) ++eHi;

  // staging: per line, lane L -> row L>>3, LDS granule L&7; global granule
  // pre-swizzled (L&7)^(L>>3). Per wave: 4 A-lines + 4 B-lines of 8 rows.
  const int srow = lane >> 3;
  const int scol = ((lane & 7) ^ srow) * 8;
  const int aw = wid * 32;                        // rows 32w..32w+31 (A and B)
  const int l15 = lane & 15, l7 = lane & 7;
  const int rg = lane >> 4;                       // 0..3
  const int g0 = ((rg) ^ l7) * 8;                 // kk0 read granule (shorts)
  const int g1 = ((4 + rg) ^ l7) * 8;             // kk1 read granule

  const unsigned short* Ab = A + (size_t)r0 * K;

  for (int e = eLo; e <= eHi; ++e) {
    const unsigned short* Bb = B + (size_t)e * H_DIM * K + (size_t)c0 * K;
    f32x4 acc[8][4];
#pragma unroll
    for (int mi = 0; mi < 8; ++mi)
#pragma unroll
      for (int ni = 0; ni < 4; ++ni) acc[mi][ni] = (f32x4){0.f, 0.f, 0.f, 0.f};

#define SA1(T, J, BN) gload16(Ab + (size_t)(aw + (J) * 8 + srow) * K + (size_t)(T) * 64 + scol, \
                              &lA[(BN) * AT + (aw + (J) * 8) * 64])
#define SB1(T, J, BN) gload16(Bb + (size_t)(aw + (J) * 8 + srow) * K + (size_t)(T) * 64 + scol, \
                              &lB[(BN) * AT + (aw + (J) * 8) * 64])
#define STG(T, BN) do { SA1(T, 0, BN); SA1(T, 1, BN); SA1(T, 2, BN); SA1(T, 3, BN); \
                        SB1(T, 0, BN); SB1(T, 1, BN); SB1(T, 2, BN); SB1(T, 3, BN); } while (0)
#define RDA(BI, G, FA) do { _Pragma("unroll") for (int m_ = 0; m_ < 8; ++m_) \
    FA[m_] = *(const bf16x8*)&lA[(BI) * AT + (wr * 128 + m_ * 16 + l15) * 64 + (G)]; } while (0)
#define RDB(BI, G, FB) do { _Pragma("unroll") for (int n_ = 0; n_ < 4; ++n_) \
    FB[n_] = *(const bf16x8*)&lB[(BI) * AT + (wc * 64 + n_ * 16 + l15) * 64 + (G)]; } while (0)
#define MM1(FA, FB) do { \
    __builtin_amdgcn_s_setprio(1); \
    _Pragma("unroll") for (int m_ = 0; m_ < 8; ++m_) \
      _Pragma("unroll") for (int n_ = 0; n_ < 4; ++n_) \
        acc[m_][n_] = __builtin_amdgcn_mfma_f32_16x16x32_bf16(FA[m_], FB[n_], acc[m_][n_], 0, 0, 0); \
    __builtin_amdgcn_s_setprio(0); \
  } while (0)
// One K-tile: wait own prefetch to depth 8, barrier (global arrival), read
// kk0 frags + kk1 A-frags, partial-wait, MFMA kk0 (kk1 reads' latency hides
// under it), read kk1 B-frags, drain, MFMA kk1, barrier, stage t+2.
#define KT1(T, BI, BN, WAIT, ST) do { \
    bf16x8 fa0[8], fb0[4], fa1[8], fb1[4]; \
    WAIT; SBAR(); \
    RDA(BI, g0, fa0); RDB(BI, g0, fb0); RDA(BI, g1, fa1); \
    LGKMN(8); \
    MM1(fa0, fb0); \
    RDB(BI, g1, fb1); \
    LGKM0(); \
    MM1(fa1, fb1); \
    SBAR(); \
    if (ST) STG((T) + 2, BN); \
  } while (0)

    STG(0, 0);
    STG(1, 1);

#pragma unroll 1
    for (int t = 0; t < NT - 2; ++t) {
      KT1(t, (t & 1), (t & 1), VMW(8), true);
    }
    KT1(NT - 2, ((NT - 2) & 1), 0, VMW(8), false);
    KT1(NT - 1, ((NT - 1) & 1), 0, VMW(0), false);

    // epilogue: C/D layout col=lane&15, row=(lane>>4)*4+reg
    const int segLo = csum[e], segHi = csum[e + 1];
#pragma unroll
    for (int mi = 0; mi < 8; ++mi) {
      const int rowb = r0 + wr * 128 + mi * 16 + ((lane >> 4) << 2);
#pragma unroll
      for (int ni = 0; ni < 4; ++ni) {
        const int col = c0 + wc * 64 + ni * 16 + l15;
#pragma unroll
        for (int r = 0; r < 4; ++r) {
          const int gr = rowb + r;
          if (gr >= segLo && gr < segHi) {
            float h = bf2f(f2bf(acc[mi][ni][r]));
            h = h > 0.f ? h : 0.f;
            O[(size_t)gr * H_DIM + col] = f2bf(h * h);
          }
        }
      }
    }
#undef SA1
#undef SB1
#undef STG
#undef RDA
#undef RDB
#undef MM1
#undef KT1
  }
}

// ---------------------------------------------------------------------------
// GEMM2 — UNCHANGED measured R5 kernel (52us): BM=256 BN=128 BK=64, 8 waves
// 4Mx2N, 2 phases/K-tile, counted vmcnt(6), 4 K-half LDS slots, XOR swizzle.
// ---------------------------------------------------------------------------
template <int K, int N>
__global__ __launch_bounds__(512, 2)
void ggemm2(const unsigned short* __restrict__ A,
            const unsigned short* __restrict__ B,
            const int* __restrict__ counts,
            float* __restrict__ OF) {
  constexpr int NT = K / 64;
  constexpr int NCB = N / 128;
  __shared__ short lA[4 * 8192];
  __shared__ short lB[4 * 4096];

  const int tid = threadIdx.x;
  const int wid = tid >> 6, lane = tid & 63;
  const int wr = wid >> 1, wc = wid & 1;
  const int bid = blockIdx.x;
  const int cb = bid % NCB, rb = bid / NCB;
  const int r0 = rb * 256, c0 = cb * 128;

  int csum[N_EXPERTS + 1];
  csum[0] = 0;
  for (int e = 0; e < N_EXPERTS; ++e) csum[e + 1] = csum[e] + counts[e];
  int eLo = 0;
  while (eLo < N_EXPERTS - 1 && csum[eLo + 1] <= r0) ++eLo;
  int eHi = eLo;
  while (eHi < N_EXPERTS - 1 && csum[eHi + 1] < r0 + 256) ++eHi;

  const int srow = lane >> 2;
  const int scol = ((lane & 3) ^ ((lane >> 3) & 3)) * 8;
  const size_t aBase = (size_t)(r0 + wid * 16 + srow) * K + scol;
  const size_t bBase0 = (size_t)(c0 + wid * 16 + srow) * K + scol;
  const int ldsW = wid * 512;
  const int l15 = lane & 15;
  const int l4 = ((lane >> 4) ^ ((lane >> 1) & 3)) * 8;

  for (int e = eLo; e <= eHi; ++e) {
    const unsigned short* Be = B + (size_t)e * N * K;
    f32x4 acc[4][4];
#pragma unroll
    for (int mi = 0; mi < 4; ++mi)
#pragma unroll
      for (int ni = 0; ni < 4; ++ni) acc[mi][ni] = (f32x4){0.f, 0.f, 0.f, 0.f};

#define STAGE_A(t, h) do { const int s_ = (((t) & 1) << 1) | (h); \
    gload16(A + aBase + (size_t)(t) * 64 + (h) * 32,                 &lA[s_ * 8192 + ldsW]); \
    gload16(A + aBase + (size_t)128 * K + (size_t)(t) * 64 + (h) * 32, &lA[s_ * 8192 + ldsW + 4096]); } while (0)
#define STAGE_B(t, h) do { const int s_ = (((t) & 1) << 1) | (h); \
    gload16(Be + bBase0 + (size_t)(t) * 64 + (h) * 32, &lB[s_ * 4096 + ldsW]); } while (0)
#define G_RD(SLOT) do { \
    _Pragma("unroll") for (int m_ = 0; m_ < 4; ++m_) \
      fa[m_] = *(const bf16x8*)&lA[(SLOT) * 8192 + (wr * 64 + m_ * 16 + l15) * 32 + l4]; \
    _Pragma("unroll") for (int n_ = 0; n_ < 4; ++n_) \
      fb[n_] = *(const bf16x8*)&lB[(SLOT) * 4096 + (wc * 64 + n_ * 16 + l15) * 32 + l4]; \
  } while (0)
#define G_MM() do { \
    __builtin_amdgcn_s_setprio(1); \
    _Pragma("unroll") for (int m_ = 0; m_ < 4; ++m_) \
      _Pragma("unroll") for (int n_ = 0; n_ < 4; ++n_) \
        acc[m_][n_] = __builtin_amdgcn_mfma_f32_16x16x32_bf16(fa[m_], fb[n_], acc[m_][n_], 0, 0, 0); \
    __builtin_amdgcn_s_setprio(0); \
  } while (0)

    STAGE_A(0, 0); STAGE_B(0, 0); STAGE_A(0, 1); STAGE_B(0, 1);
    STAGE_A(1, 0); STAGE_B(1, 0);
    VMW(6); SBAR();

#pragma unroll 1
    for (int t = 0; t < NT - 2; ++t) {
      const int k0 = ((t & 1) << 1), k1 = k0 | 1;
      { bf16x8 fa[4], fb[4]; G_RD(k0); STAGE_A(t + 1, 1); STAGE_B(t + 1, 1); VMW(6); LGKM0(); G_MM(); SBAR(); }
      { bf16x8 fa[4], fb[4]; G_RD(k1); STAGE_A(t + 2, 0); STAGE_B(t + 2, 0); VMW(6); LGKM0(); G_MM(); SBAR(); }
    }
    {
      const int k0 = (((NT - 2) & 1) << 1), k1 = k0 | 1;
      { bf16x8 fa[4], fb[4]; G_RD(k0); STAGE_A(NT - 1, 1); STAGE_B(NT - 1, 1); VMW(6); LGKM0(); G_MM(); SBAR(); }
      { bf16x8 fa[4], fb[4]; G_RD(k1);                                        VMW(3); LGKM0(); G_MM(); SBAR(); }
    }
    {
      const int k0 = (((NT - 1) & 1) << 1), k1 = k0 | 1;
      { bf16x8 fa[4], fb[4]; G_RD(k0);                                        VMW(0); LGKM0(); G_MM(); SBAR(); }
      { bf16x8 fa[4], fb[4]; G_RD(k1);                                                LGKM0(); G_MM(); SBAR(); }
    }

    const int segLo = csum[e], segHi = csum[e + 1];
#pragma unroll
    for (int mi = 0; mi < 4; ++mi) {
      const int rowb = r0 + wr * 64 + mi * 16 + ((lane >> 4) << 2);
#pragma unroll
      for (int ni = 0; ni < 4; ++ni) {
        const int col = c0 + wc * 64 + ni * 16 + l15;
#pragma unroll
        for (int r = 0; r < 4; ++r) {
          const int gr = rowb + r;
          if (gr >= segLo && gr < segHi) {
            OF[(size_t)gr * N + col] = bf2f(f2bf(acc[mi][ni][r]));
          }
        }
      }
    }
#undef STAGE_A
#undef STAGE_B
#undef G_RD
#undef G_MM
  }
}

extern "C" void kernel_launch(void* const* d_in, const int* in_sizes, int n_in,
                              void* d_out, int out_size, void* d_ws, size_t ws_size,
                              hipStream_t stream) {
  const float* x = (const float*)d_in[0];
  const float* w_up = (const float*)d_in[1];
  const float* w_down = (const float*)d_in[2];
  const int* counts = (const int*)d_in[3];
  float* out = (float*)d_out;

  char* ws = (char*)d_ws;
  unsigned short* xb  = (unsigned short*)(ws);
  unsigned short* wub = (unsigned short*)(ws + (size_t)16 * 1024 * 1024);
  unsigned short* wdb = (unsigned short*)(ws + (size_t)48 * 1024 * 1024);
  unsigned short* hsq = (unsigned short*)(ws + (size_t)80 * 1024 * 1024);

  cvt_f32_bf16_kernel<<<2048, 256, 0, stream>>>(x, xb, T_TOKENS * D_DIM);
  cvt_f32_bf16_kernel<<<2048, 256, 0, stream>>>(w_up, wub, N_EXPERTS * H_DIM * D_DIM);
  cvt_f32_bf16_kernel<<<2048, 256, 0, stream>>>(w_down, wdb, N_EXPERTS * D_DIM * H_DIM);

  // GEMM1: 256x256 tile, grid 32 rb x 8 cb = 256 blocks (1/CU, cb<->XCD)
  gg1_256<<<256, 512, 0, stream>>>(xb, wub, counts, hsq);
  // GEMM2: unchanged R5 structure; grid 32 rb x 8 cb = 256 blocks
  ggemm2<H_DIM, D_DIM>
      <<<(T_TOKENS / 256) * (D_DIM / 128), 512, 0, stream>>>(hsq, wdb, counts, out);
}

// Round 8
// 183.065 us; speedup vs baseline: 1.0015x; 1.0015x over previous
//
#include <hip/hip_runtime.h>
#include <hip/hip_bf16.h>
#include <stdint.h>

#define T_TOKENS 8192
#define D_DIM 1024
#define H_DIM 2048
#define N_EXPERTS 8

typedef __attribute__((ext_vector_type(8))) short bf16x8;
typedef __attribute__((ext_vector_type(4))) float f32x4;

typedef __attribute__((address_space(1))) const void* gptr_t;
typedef __attribute__((address_space(3))) void* lptr_t;

__device__ __forceinline__ unsigned short f2bf(float f) {
  union { float f; unsigned int u; } x; x.f = f;
  unsigned int r = x.u + 0x7FFFu + ((x.u >> 16) & 1u);
  return (unsigned short)(r >> 16);
}
__device__ __forceinline__ float bf2f(unsigned short b) {
  union { unsigned int u; float f; } x; x.u = ((unsigned int)b) << 16;
  return x.f;
}

__device__ __forceinline__ void gload16(const void* g, void* l) {
  __builtin_amdgcn_global_load_lds((gptr_t)g, (lptr_t)l, 16, 0, 0);
}

// Sync discipline (rule #18: sched_barrier after inline-asm waits / raw barriers)
#define SBAR()   do { __builtin_amdgcn_s_barrier(); __builtin_amdgcn_sched_barrier(0); } while (0)
#define LGKM0()  do { asm volatile("s_waitcnt lgkmcnt(0)" ::: "memory"); __builtin_amdgcn_sched_barrier(0); } while (0)
#define LGKMN(n) do { asm volatile("s_waitcnt lgkmcnt(" #n ")" ::: "memory"); __builtin_amdgcn_sched_barrier(0); } while (0)
#define VMW(n)   do { __builtin_amdgcn_sched_barrier(0); asm volatile("s_waitcnt vmcnt(" #n ")" ::: "memory"); } while (0)

// ---------------------------------------------------------------------------
// fp32 -> bf16 conversion — round-1 structure (~36us total; 240MB roofline).
// ---------------------------------------------------------------------------
__global__ void cvt_f32_bf16_kernel(const float* __restrict__ in,
                                    unsigned short* __restrict__ out, int n) {
  int tid = blockIdx.x * blockDim.x + threadIdx.x;
  int stride = gridDim.x * blockDim.x;
  for (int i = tid * 4; i < n; i += stride * 4) {
    const float4 v = *reinterpret_cast<const float4*>(in + i);
    ushort4 o;
    o.x = f2bf(v.x); o.y = f2bf(v.y); o.z = f2bf(v.z); o.w = f2bf(v.w);
    *reinterpret_cast<ushort4*>(out + i) = o;
  }
}

// ---------------------------------------------------------------------------
// GEMM1: hsq[T,H] = bf16(relu(bf16(x @ w_up^T))^2).
// BM=256 BN=256 BK=64, 8 waves 2Mx4N, wave-tile 128x64 (acc[8][4] -> AGPR).
// R7 FAILURE FIX: fragment reads PHASE-SPLIT (4 clusters of 16 MFMA, each
// preceded by its 4-8 ds_reads with counted in-order lgkmcnt) so peak live
// fragments = 16 (64 VGPR) instead of 24+ -> no scratch spill (R7: WRITE_SIZE
// 103MB vs 32MB output = spill traffic; MfmaUtil 16%).
// LDS ring-2 full K-tiles: lA 2x[256][64] + lB 2x[256][64] = 128KB, 1 blk/CU.
// Per tile: VMW(8), SBAR, 4x{reads, lgkmcnt, 16 MFMA}, SBAR, stage(t+2).
// XOR swizzle (rule #21): stage pre-swizzles GLOBAL granule (lane&7)^(lane>>3),
// LDS dest linear; read granule (kk*4+rg)^(row&7).
// ---------------------------------------------------------------------------
__global__ __launch_bounds__(512, 2)
void gg1_256(const unsigned short* __restrict__ A,  // (T, D) bf16
             const unsigned short* __restrict__ B,  // (E, H, D) bf16
             const int* __restrict__ counts,
             unsigned short* __restrict__ O) {      // (T, H) bf16
  constexpr int K = D_DIM;
  constexpr int NT = K / 64;      // 16
  constexpr int AT = 256 * 64;    // shorts per tile buffer
  __shared__ short lA[2 * AT];    // 64 KB
  __shared__ short lB[2 * AT];    // 64 KB

  const int tid = threadIdx.x;
  const int wid = tid >> 6, lane = tid & 63;
  const int wr = wid >> 2, wc = wid & 3;          // 2M x 4N
  const int bid = blockIdx.x;
  const int cb = bid & 7, rb = bid >> 3;          // cb <-> XCD (grid 256)
  const int r0 = rb * 256, c0 = cb * 256;

  int csum[N_EXPERTS + 1];
  csum[0] = 0;
  for (int e = 0; e < N_EXPERTS; ++e) csum[e + 1] = csum[e] + counts[e];
  int eLo = 0;
  while (eLo < N_EXPERTS - 1 && csum[eLo + 1] <= r0) ++eLo;
  int eHi = eLo;
  while (eHi < N_EXPERTS - 1 && csum[eHi + 1] < r0 + 256) ++eHi;

  // staging: per line, lane L -> row L>>3, LDS granule L&7; global granule
  // pre-swizzled (L&7)^(L>>3). Per wave: 4 A-lines + 4 B-lines of 8 rows.
  const int srow = lane >> 3;
  const int scol = ((lane & 7) ^ srow) * 8;
  const int aw = wid * 32;
  const int l15 = lane & 15, l7 = lane & 7;
  const int rg = lane >> 4;                       // 0..3
  const int g0 = ((rg) ^ l7) * 8;                 // kk0 read granule (shorts)
  const int g1 = ((4 + rg) ^ l7) * 8;             // kk1 read granule

  const unsigned short* Ab = A + (size_t)r0 * K;

  for (int e = eLo; e <= eHi; ++e) {
    const unsigned short* Bb = B + (size_t)e * H_DIM * K + (size_t)c0 * K;
    f32x4 acc[8][4];
#pragma unroll
    for (int mi = 0; mi < 8; ++mi)
#pragma unroll
      for (int ni = 0; ni < 4; ++ni) acc[mi][ni] = (f32x4){0.f, 0.f, 0.f, 0.f};

#define SA1(T, J, BN) gload16(Ab + (size_t)(aw + (J) * 8 + srow) * K + (size_t)(T) * 64 + scol, \
                              &lA[(BN) * AT + (aw + (J) * 8) * 64])
#define SB1(T, J, BN) gload16(Bb + (size_t)(aw + (J) * 8 + srow) * K + (size_t)(T) * 64 + scol, \
                              &lB[(BN) * AT + (aw + (J) * 8) * 64])
#define STG(T, BN) do { SA1(T, 0, BN); SA1(T, 1, BN); SA1(T, 2, BN); SA1(T, 3, BN); \
                        SB1(T, 0, BN); SB1(T, 1, BN); SB1(T, 2, BN); SB1(T, 3, BN); } while (0)
// 4 A-fragment reads for m-half MH (rows wr*128 + MH*64 .. +63) at granule G
#define RDA4(BI, G, MH, FA) do { _Pragma("unroll") for (int m_ = 0; m_ < 4; ++m_) \
    FA[m_] = *(const bf16x8*)&lA[(BI) * AT + (wr * 128 + (MH) * 64 + m_ * 16 + l15) * 64 + (G)]; } while (0)
#define RDB4(BI, G, FB) do { _Pragma("unroll") for (int n_ = 0; n_ < 4; ++n_) \
    FB[n_] = *(const bf16x8*)&lB[(BI) * AT + (wc * 64 + n_ * 16 + l15) * 64 + (G)]; } while (0)
// 16 MFMA: m-half MH x 4 n
#define MM4(FA, FB, MH) do { \
    __builtin_amdgcn_s_setprio(1); \
    _Pragma("unroll") for (int m_ = 0; m_ < 4; ++m_) \
      _Pragma("unroll") for (int n_ = 0; n_ < 4; ++n_) \
        acc[(MH) * 4 + m_][n_] = __builtin_amdgcn_mfma_f32_16x16x32_bf16(FA[m_], FB[n_], acc[(MH) * 4 + m_][n_], 0, 0, 0); \
    __builtin_amdgcn_s_setprio(0); \
  } while (0)
// One K-tile, 4 phases. DS ops retire in order -> counted lgkmcnt isolates
// each phase's reads while the next phase's reads overlap the current MFMAs.
#define KT1(T, BI, BN, WAIT, ST) do { \
    bf16x8 faL0[4], faH0[4], faL1[4], faH1[4], fb0[4], fb1[4]; \
    WAIT; SBAR(); \
    RDA4(BI, g0, 0, faL0); RDB4(BI, g0, fb0);  /* 8 reads */ \
    RDA4(BI, g0, 1, faH0);                     /* 4 reads */ \
    LGKMN(4); \
    MM4(faL0, fb0, 0); \
    RDA4(BI, g1, 0, faL1); RDB4(BI, g1, fb1);  /* 8 reads */ \
    LGKMN(8); \
    MM4(faH0, fb0, 1); \
    RDA4(BI, g1, 1, faH1);                     /* 4 reads */ \
    LGKMN(4); \
    MM4(faL1, fb1, 0); \
    LGKM0(); \
    MM4(faH1, fb1, 1); \
    SBAR(); \
    if (ST) STG((T) + 2, BN); \
  } while (0)

    STG(0, 0);
    STG(1, 1);

#pragma unroll 1
    for (int t = 0; t < NT - 2; ++t) {
      KT1(t, (t & 1), (t & 1), VMW(8), true);
    }
    KT1(NT - 2, ((NT - 2) & 1), 0, VMW(8), false);
    KT1(NT - 1, ((NT - 1) & 1), 0, VMW(0), false);

    // epilogue: C/D layout col=lane&15, row=(lane>>4)*4+reg
    const int segLo = csum[e], segHi = csum[e + 1];
#pragma unroll
    for (int mi = 0; mi < 8; ++mi) {
      const int rowb = r0 + wr * 128 + mi * 16 + ((lane >> 4) << 2);
#pragma unroll
      for (int ni = 0; ni < 4; ++ni) {
        const int col = c0 + wc * 64 + ni * 16 + l15;
#pragma unroll
        for (int r = 0; r < 4; ++r) {
          const int gr = rowb + r;
          if (gr >= segLo && gr < segHi) {
            float h = bf2f(f2bf(acc[mi][ni][r]));
            h = h > 0.f ? h : 0.f;
            O[(size_t)gr * H_DIM + col] = f2bf(h * h);
          }
        }
      }
    }
#undef SA1
#undef SB1
#undef STG
#undef RDA4
#undef RDB4
#undef MM4
#undef KT1
  }
}

// ---------------------------------------------------------------------------
// GEMM2 — unchanged measured R5 kernel: BM=256 BN=128 BK=64, 8 waves 4Mx2N,
// 2 phases/K-tile, counted vmcnt(6), 4 K-half LDS slots, XOR swizzle.
// ---------------------------------------------------------------------------
template <int K, int N>
__global__ __launch_bounds__(512, 2)
void ggemm2(const unsigned short* __restrict__ A,
            const unsigned short* __restrict__ B,
            const int* __restrict__ counts,
            float* __restrict__ OF) {
  constexpr int NT = K / 64;
  constexpr int NCB = N / 128;
  __shared__ short lA[4 * 8192];
  __shared__ short lB[4 * 4096];

  const int tid = threadIdx.x;
  const int wid = tid >> 6, lane = tid & 63;
  const int wr = wid >> 1, wc = wid & 1;
  const int bid = blockIdx.x;
  const int cb = bid % NCB, rb = bid / NCB;
  const int r0 = rb * 256, c0 = cb * 128;

  int csum[N_EXPERTS + 1];
  csum[0] = 0;
  for (int e = 0; e < N_EXPERTS; ++e) csum[e + 1] = csum[e] + counts[e];
  int eLo = 0;
  while (eLo < N_EXPERTS - 1 && csum[eLo + 1] <= r0) ++eLo;
  int eHi = eLo;
  while (eHi < N_EXPERTS - 1 && csum[eHi + 1] < r0 + 256) ++eHi;

  const int srow = lane >> 2;
  const int scol = ((lane & 3) ^ ((lane >> 3) & 3)) * 8;
  const size_t aBase = (size_t)(r0 + wid * 16 + srow) * K + scol;
  const size_t bBase0 = (size_t)(c0 + wid * 16 + srow) * K + scol;
  const int ldsW = wid * 512;
  const int l15 = lane & 15;
  const int l4 = ((lane >> 4) ^ ((lane >> 1) & 3)) * 8;

  for (int e = eLo; e <= eHi; ++e) {
    const unsigned short* Be = B + (size_t)e * N * K;
    f32x4 acc[4][4];
#pragma unroll
    for (int mi = 0; mi < 4; ++mi)
#pragma unroll
      for (int ni = 0; ni < 4; ++ni) acc[mi][ni] = (f32x4){0.f, 0.f, 0.f, 0.f};

#define STAGE_A(t, h) do { const int s_ = (((t) & 1) << 1) | (h); \
    gload16(A + aBase + (size_t)(t) * 64 + (h) * 32,                 &lA[s_ * 8192 + ldsW]); \
    gload16(A + aBase + (size_t)128 * K + (size_t)(t) * 64 + (h) * 32, &lA[s_ * 8192 + ldsW + 4096]); } while (0)
#define STAGE_B(t, h) do { const int s_ = (((t) & 1) << 1) | (h); \
    gload16(Be + bBase0 + (size_t)(t) * 64 + (h) * 32, &lB[s_ * 4096 + ldsW]); } while (0)
#define G_RD(SLOT) do { \
    _Pragma("unroll") for (int m_ = 0; m_ < 4; ++m_) \
      fa[m_] = *(const bf16x8*)&lA[(SLOT) * 8192 + (wr * 64 + m_ * 16 + l15) * 32 + l4]; \
    _Pragma("unroll") for (int n_ = 0; n_ < 4; ++n_) \
      fb[n_] = *(const bf16x8*)&lB[(SLOT) * 4096 + (wc * 64 + n_ * 16 + l15) * 32 + l4]; \
  } while (0)
#define G_MM() do { \
    __builtin_amdgcn_s_setprio(1); \
    _Pragma("unroll") for (int m_ = 0; m_ < 4; ++m_) \
      _Pragma("unroll") for (int n_ = 0; n_ < 4; ++n_) \
        acc[m_][n_] = __builtin_amdgcn_mfma_f32_16x16x32_bf16(fa[m_], fb[n_], acc[m_][n_], 0, 0, 0); \
    __builtin_amdgcn_s_setprio(0); \
  } while (0)

    STAGE_A(0, 0); STAGE_B(0, 0); STAGE_A(0, 1); STAGE_B(0, 1);
    STAGE_A(1, 0); STAGE_B(1, 0);
    VMW(6); SBAR();

#pragma unroll 1
    for (int t = 0; t < NT - 2; ++t) {
      const int k0 = ((t & 1) << 1), k1 = k0 | 1;
      { bf16x8 fa[4], fb[4]; G_RD(k0); STAGE_A(t + 1, 1); STAGE_B(t + 1, 1); VMW(6); LGKM0(); G_MM(); SBAR(); }
      { bf16x8 fa[4], fb[4]; G_RD(k1); STAGE_A(t + 2, 0); STAGE_B(t + 2, 0); VMW(6); LGKM0(); G_MM(); SBAR(); }
    }
    {
      const int k0 = (((NT - 2) & 1) << 1), k1 = k0 | 1;
      { bf16x8 fa[4], fb[4]; G_RD(k0); STAGE_A(NT - 1, 1); STAGE_B(NT - 1, 1); VMW(6); LGKM0(); G_MM(); SBAR(); }
      { bf16x8 fa[4], fb[4]; G_RD(k1);                                        VMW(3); LGKM0(); G_MM(); SBAR(); }
    }
    {
      const int k0 = (((NT - 1) & 1) << 1), k1 = k0 | 1;
      { bf16x8 fa[4], fb[4]; G_RD(k0);                                        VMW(0); LGKM0(); G_MM(); SBAR(); }
      { bf16x8 fa[4], fb[4]; G_RD(k1);                                                LGKM0(); G_MM(); SBAR(); }
    }

    const int segLo = csum[e], segHi = csum[e + 1];
#pragma unroll
    for (int mi = 0; mi < 4; ++mi) {
      const int rowb = r0 + wr * 64 + mi * 16 + ((lane >> 4) << 2);
#pragma unroll
      for (int ni = 0; ni < 4; ++ni) {
        const int col = c0 + wc * 64 + ni * 16 + l15;
#pragma unroll
        for (int r = 0; r < 4; ++r) {
          const int gr = rowb + r;
          if (gr >= segLo && gr < segHi) {
            OF[(size_t)gr * N + col] = bf2f(f2bf(acc[mi][ni][r]));
          }
        }
      }
    }
#undef STAGE_A
#undef STAGE_B
#undef G_RD
#undef G_MM
  }
}

extern "C" void kernel_launch(void* const* d_in, const int* in_sizes, int n_in,
                              void* d_out, int out_size, void* d_ws, size_t ws_size,
                              hipStream_t stream) {
  const float* x = (const float*)d_in[0];
  const float* w_up = (const float*)d_in[1];
  const float* w_down = (const float*)d_in[2];
  const int* counts = (const int*)d_in[3];
  float* out = (float*)d_out;

  char* ws = (char*)d_ws;
  unsigned short* xb  = (unsigned short*)(ws);
  unsigned short* wub = (unsigned short*)(ws + (size_t)16 * 1024 * 1024);
  unsigned short* wdb = (unsigned short*)(ws + (size_t)48 * 1024 * 1024);
  unsigned short* hsq = (unsigned short*)(ws + (size_t)80 * 1024 * 1024);

  cvt_f32_bf16_kernel<<<2048, 256, 0, stream>>>(x, xb, T_TOKENS * D_DIM);
  cvt_f32_bf16_kernel<<<2048, 256, 0, stream>>>(w_up, wub, N_EXPERTS * H_DIM * D_DIM);
  cvt_f32_bf16_kernel<<<2048, 256, 0, stream>>>(w_down, wdb, N_EXPERTS * D_DIM * H_DIM);

  // GEMM1: 256x256 tile, grid 32 rb x 8 cb = 256 blocks (1/CU, cb<->XCD)
  gg1_256<<<256, 512, 0, stream>>>(xb, wub, counts, hsq);
  // GEMM2: R5 structure; grid 32 rb x 8 cb = 256 blocks
  ggemm2<H_DIM, D_DIM>
      <<<(T_TOKENS / 256) * (D_DIM / 128), 512, 0, stream>>>(hsq, wdb, counts, out);
}